// Round 1
// baseline (1714.050 us; speedup 1.0000x reference)
//
#include <hip/hip_runtime.h>
#include <hip/hip_bf16.h>
#include <cstdint>

// Problem constants
#define Bsz 2
#define Tsz 2048
#define Hsz 1024
#define Vsz 50257
#define Msz (Bsz * Tsz)      // 4096
#define NPAD 50304           // 393 * 128, weight rows padded with zeros
#define NT 393               // N tiles
#define MT 32                // M tiles

typedef __bf16 bf16x8 __attribute__((ext_vector_type(8)));
typedef __bf16 bf16x4 __attribute__((ext_vector_type(4)));
typedef float  f32x4  __attribute__((ext_vector_type(4)));

// ---- async global->LDS 16B copy (CK-style addrspace casts) ----
__device__ __forceinline__ void load_lds16(const void* gptr, void* ldsptr) {
  auto g = (const __attribute__((address_space(1))) unsigned int*)(uintptr_t)gptr;
  auto l = (__attribute__((address_space(3))) unsigned int*)(uintptr_t)ldsptr;
  __builtin_amdgcn_global_load_lds(g, l, 16, 0, 0);
}

// ---- fp32 -> bf16 cast kernels ----
__global__ void cast_hidden_kernel(const float* __restrict__ in, __bf16* __restrict__ out) {
  // Msz*Hsz = 4194304 elements, 4 per thread
  int i = blockIdx.x * blockDim.x + threadIdx.x;
  const float4 v = ((const float4*)in)[i];
  bf16x4 o = { (__bf16)v.x, (__bf16)v.y, (__bf16)v.z, (__bf16)v.w };
  ((bf16x4*)out)[i] = o;
}

__global__ void cast_weight_kernel(const float* __restrict__ in, __bf16* __restrict__ out) {
  // NPAD*Hsz elements, 4 per thread; rows >= Vsz are zero padding.
  long i = (long)blockIdx.x * blockDim.x + threadIdx.x;
  long i4 = i * 4;
  bf16x4 o;
  if (i4 < (long)Vsz * Hsz) {
    const float4 v = ((const float4*)in)[i];
    o = (bf16x4){ (__bf16)v.x, (__bf16)v.y, (__bf16)v.z, (__bf16)v.w };
  } else {
    o = (bf16x4){ (__bf16)0.f, (__bf16)0.f, (__bf16)0.f, (__bf16)0.f };
  }
  ((bf16x4*)out)[i] = o;
}

// ---- bf16 MFMA GEMM: C[m,n] = sum_k A[m,k] * W[n,k], C fp32 ----
// 128x128 tile, BK=64, 256 threads (4 waves, 2x2), each wave 4x4 of 16x16x32.
__global__ __launch_bounds__(256) void gemm_kernel(const __bf16* __restrict__ A,
                                                   const __bf16* __restrict__ W,
                                                   float* __restrict__ C) {
  __shared__ __align__(16) __bf16 sA[128 * 64];
  __shared__ __align__(16) __bf16 sB[128 * 64];

  // tile-group swizzle: 8 M-tiles share each weight tile among co-resident blocks
  int bid = blockIdx.x;
  const int GROUP = 8;
  const int in_group = GROUP * NT;          // 3144
  int group = bid / in_group;
  int rem   = bid % in_group;
  int m_tile = group * GROUP + (rem % GROUP);
  int n_tile = rem / GROUP;
  const int m0 = m_tile * 128;
  const int n0 = n_tile * 128;

  const int tid  = threadIdx.x;
  const int lane = tid & 63;
  const int wid  = tid >> 6;
  const int wave_m = wid & 1;
  const int wave_n = wid >> 1;

  // staging geometry: per wave-iter, 64 lanes x 16B = 8 rows x 64 bf16
  const int r_local = lane >> 3;   // row within 8-row group
  const int s_slot  = lane & 7;    // LDS chunk slot within row
  const int g_chunk = s_slot ^ r_local;  // XOR swizzle: fetch this global chunk

  // fragment read offsets (elements), ko2=0; ko2=1 is ^32
  const int fr = lane & 15;
  const int q  = lane >> 4;
  int a_off[4], b_off[4];
#pragma unroll
  for (int i = 0; i < 4; ++i) {
    int ra = wave_m * 64 + i * 16 + fr;
    a_off[i] = ra * 64 + ((q ^ (ra & 7)) << 3);
    int rb = wave_n * 64 + i * 16 + fr;
    b_off[i] = rb * 64 + ((q ^ (rb & 7)) << 3);
  }

  f32x4 acc[4][4];
#pragma unroll
  for (int mi = 0; mi < 4; ++mi)
#pragma unroll
    for (int ni = 0; ni < 4; ++ni)
      acc[mi][ni] = (f32x4){0.f, 0.f, 0.f, 0.f};

  const __bf16* Ab = A + (size_t)m0 * Hsz;
  const __bf16* Wb = W + (size_t)n0 * Hsz;

  for (int kt = 0; kt < Hsz / 64; ++kt) {
    if (kt) __syncthreads();      // protect LDS reuse
    const int kcol = kt * 64 + g_chunk * 8;
#pragma unroll
    for (int j = 0; j < 4; ++j) {
      const int idx = wid * 4 + j;            // 0..15 wave-iterations
      const int row = idx * 8 + r_local;      // tile row
      load_lds16(Ab + (size_t)row * Hsz + kcol, &sA[idx * 512 + lane * 8]);
      load_lds16(Wb + (size_t)row * Hsz + kcol, &sB[idx * 512 + lane * 8]);
    }
    __syncthreads();              // drain global_load_lds (vmcnt) + visibility

#pragma unroll
    for (int half = 0; half < 2; ++half) {
      const int x = half << 5;    // ^32 elements flips chunk bit 2
      bf16x8 af[4], bfr[4];
#pragma unroll
      for (int i = 0; i < 4; ++i) af[i]  = *(const bf16x8*)&sA[a_off[i] ^ x];
#pragma unroll
      for (int i = 0; i < 4; ++i) bfr[i] = *(const bf16x8*)&sB[b_off[i] ^ x];
#pragma unroll
      for (int mi = 0; mi < 4; ++mi)
#pragma unroll
        for (int ni = 0; ni < 4; ++ni)
          acc[mi][ni] = __builtin_amdgcn_mfma_f32_16x16x32_bf16(af[mi], bfr[ni], acc[mi][ni], 0, 0, 0);
    }
  }

  // epilogue: C/D layout col=lane&15, row=(lane>>4)*4+reg  [m89-verified]
#pragma unroll
  for (int mi = 0; mi < 4; ++mi) {
    const int row = m0 + wave_m * 64 + mi * 16 + q * 4;
#pragma unroll
    for (int ni = 0; ni < 4; ++ni) {
      const int col = n0 + wave_n * 64 + ni * 16 + fr;
      if (col < Vsz) {
        float* cp = C + (size_t)row * Vsz + col;
#pragma unroll
        for (int r = 0; r < 4; ++r)
          cp[(size_t)r * Vsz] = acc[mi][ni][r];
      }
    }
  }
}

// ---- loss: one block per shifted row; online logsumexp over V ----
__global__ __launch_bounds__(256) void loss_kernel(const float* __restrict__ logits,
                                                   const int* __restrict__ labels,
                                                   float* __restrict__ accum) {
  const int i = blockIdx.x;           // 0 .. B*(T-1)-1 = 4093
  const int b = i / (Tsz - 1);
  const int t = i % (Tsz - 1);
  const long row = (long)b * Tsz + t;
  const float* x = logits + row * (long)Vsz;

  const int tid = threadIdx.x;
  float m = -INFINITY, s = 0.f;
  for (int v = tid; v < Vsz; v += 256) {
    float val = x[v];
    float M = fmaxf(m, val);
    s = s * __expf(m - M) + __expf(val - M);
    m = M;
  }
  // wave reduce (64 lanes)
#pragma unroll
  for (int off = 32; off > 0; off >>= 1) {
    float m2 = __shfl_xor(m, off, 64);
    float s2 = __shfl_xor(s, off, 64);
    float M = fmaxf(m, m2);
    s = s * __expf(m - M) + s2 * __expf(m2 - M);
    m = M;
  }
  __shared__ float sm[4], ss[4];
  const int lane = tid & 63, wid = tid >> 6;
  if (lane == 0) { sm[wid] = m; ss[wid] = s; }
  __syncthreads();
  if (tid == 0) {
    float M = sm[0], S = ss[0];
#pragma unroll
    for (int w = 1; w < 4; ++w) {
      float Mn = fmaxf(M, sm[w]);
      S = S * __expf(M - Mn) + ss[w] * __expf(sm[w] - Mn);
      M = Mn;
    }
    float lse = M + logf(S);
    int lab = labels[(long)b * Tsz + t + 1];
    if (lab != -1) {
      float nll = lse - x[lab];
      atomicAdd(&accum[0], nll);
      atomicAdd(&accum[1], 1.0f);
    }
  }
}

__global__ void zero_accum_kernel(float* accum) {
  accum[0] = 0.f;
  accum[1] = 0.f;
}

__global__ void finalize_kernel(const float* __restrict__ accum, float* __restrict__ out_loss) {
  out_loss[0] = accum[0] / fmaxf(accum[1], 1.0f);
}

extern "C" void kernel_launch(void* const* d_in, const int* in_sizes, int n_in,
                              void* d_out, int out_size, void* d_ws, size_t ws_size,
                              hipStream_t stream) {
  const float* hidden = (const float*)d_in[0];   // [2,2048,1024] fp32
  const float* weight = (const float*)d_in[1];   // [50257,1024] fp32
  const int*   labels = (const int*)d_in[2];     // [2,2048] int
  float* out = (float*)d_out;                    // logits flat then loss scalar

  // ws layout: A_bf16 (8 MB) | W_bf16 padded (103 MB) | accum (2 floats)
  __bf16* Abf = (__bf16*)d_ws;
  __bf16* Wbf = Abf + (size_t)Msz * Hsz;
  float* accum = (float*)((char*)d_ws + ((size_t)Msz * Hsz + (size_t)NPAD * Hsz) * sizeof(__bf16));

  zero_accum_kernel<<<1, 1, 0, stream>>>(accum);

  cast_hidden_kernel<<<(Msz * Hsz / 4) / 256, 256, 0, stream>>>(hidden, Abf);
  cast_weight_kernel<<<((size_t)NPAD * Hsz / 4) / 256, 256, 0, stream>>>(weight, Wbf);

  gemm_kernel<<<MT * NT, 256, 0, stream>>>(Abf, Wbf, out);

  loss_kernel<<<Bsz * (Tsz - 1), 256, 0, stream>>>(out, labels, accum);

  finalize_kernel<<<1, 1, 0, stream>>>(accum, out + (size_t)Msz * Vsz);
}